// Round 20
// baseline (87.669 us; speedup 1.0000x reference)
//
#include <hip/hip_runtime.h>
#include <math.h>

#define NW   64      // windows (B_)
#define NTOK 256     // tokens per window (N)
#define CDIM 128     // channels (C)
#define NH   4       // heads (H)
#define HD   32      // head dim
#define TKIN 64      // incoming topk
#define TKOUT 32     // outgoing topk
#define KSTR 36      // K/V LDS row stride (multiple of 4 -> 16B-aligned rows)

typedef float f32x2 __attribute__((ext_vector_type(2)));
typedef short bf16x8 __attribute__((ext_vector_type(8)));   // MFMA A/B frag
typedef float f32x4  __attribute__((ext_vector_type(4)));   // MFMA C/D frag

// DPP lane move (VALU pipe, ~2-4 cyc vs ~40 for ds_bpermute).
template <int CTRL>
static __device__ __forceinline__ float dpp_mov_f(float x) {
  return __int_as_float(__builtin_amdgcn_update_dpp(
      0, __float_as_int(x), CTRL, 0xF, 0xF, true));
}

// Exact full-wave max. Verified round 14. DO NOT TOUCH.
static __device__ __forceinline__ float wave_max64f(float x) {
  x = fmaxf(x, dpp_mov_f<0xB1>(x));    // lane^1
  x = fmaxf(x, dpp_mov_f<0x4E>(x));    // lane^2
  x = fmaxf(x, dpp_mov_f<0x124>(x));   // row_ror:4
  x = fmaxf(x, dpp_mov_f<0x128>(x));   // row_ror:8
  x = fmaxf(x, __int_as_float(
      __builtin_amdgcn_ds_swizzle(__float_as_int(x), 0x401F)));  // lane^16
  x = fmaxf(x, __shfl_xor(x, 32));                               // lane^32
  return x;
}

// Classic Cephes expf (np reference bit-match, round 6). DO NOT TOUCH.
static __device__ __forceinline__ float cephes_expf(float x) {
  x = fminf(x, 88.3762626647949f);
  x = fmaxf(x, -88.3762626647949f);
  float fx = __fadd_rn(__fmul_rn(x, 1.44269504088896341f), 0.5f);
  fx = floorf(fx);
  float tmp = __fmul_rn(fx, 0.693359375f);
  float z2  = __fmul_rn(fx, -2.12194440e-4f);
  x = __fsub_rn(x, tmp);
  x = __fsub_rn(x, z2);
  float z = __fmul_rn(x, x);
  float y = 1.9875691500E-4f;
  y = __fadd_rn(__fmul_rn(y, x), 1.3981999507E-3f);
  y = __fadd_rn(__fmul_rn(y, x), 8.3334519073E-3f);
  y = __fadd_rn(__fmul_rn(y, x), 4.1665795894E-2f);
  y = __fadd_rn(__fmul_rn(y, x), 1.6666665459E-1f);
  y = __fadd_rn(__fmul_rn(y, x), 5.0000001201E-1f);
  y = __fadd_rn(__fmul_rn(y, z), x);
  y = __fadd_rn(y, 1.0f);
  int n = __float2int_rz(fx);              // fx is integral
  float p2n = __int_as_float((n + 127) << 23);
  return __fmul_rn(y, p2n);
}

// numpy pairwise_sum n=64, bit-exact, DPP stage-2. Verified r14. DO NOT TOUCH.
static __device__ __forceinline__ float np_pairwise_sum64(float x, int lane) {
  int k = lane & 7;
  float r = __shfl(x, k);
  #pragma unroll
  for (int i2 = 1; i2 < 8; ++i2) r = __fadd_rn(r, __shfl(x, k + 8 * i2));
  float u = __fadd_rn(r, dpp_mov_f<0xB1>(r));    // + r[l^1]
  float v = __fadd_rn(u, dpp_mov_f<0x4E>(u));    // + u[l^2]
  float w = __fadd_rn(v, dpp_mov_f<0x124>(v));   // + v[l^4]
  return w;
}

// np einsum dot emulation, packed-f32, b128 K reads. Verified r10/r14.
// DO NOT TOUCH.
static __device__ __forceinline__ float np_dot32(const float4* __restrict__ q4,
                                                 const float* __restrict__ krow,
                                                 float scale) {
#pragma clang fp contract(off)
  const float4* k4p = (const float4*)krow;  // 16B-aligned
  f32x2 sc; sc.x = scale; sc.y = scale;
  f32x2 A01; A01.x = 0.0f; A01.y = 0.0f;
  f32x2 A23; A23.x = 0.0f; A23.y = 0.0f;
  #pragma unroll
  for (int i4 = 0; i4 < 8; ++i4) {
    float4 q = q4[i4];
    float4 kk = k4p[i4];
    f32x2 q01; q01.x = q.x; q01.y = q.y;
    f32x2 q23; q23.x = q.z; q23.y = q.w;
    f32x2 k01; k01.x = kk.x; k01.y = kk.y;
    f32x2 k23; k23.x = kk.z; k23.y = kk.w;
    A01 = A01 + (q01 * sc) * k01;
    A23 = A23 + (q23 * sc) * k23;
  }
  f32x2 R = A01 + A23;                    // (acc0+acc2, acc1+acc3)
  return __fadd_rn(R.x, R.y);
}

// f32 -> bf16, round-to-nearest-even (finite data; no NaN handling needed).
static __device__ __forceinline__ unsigned short f32_to_bf16(float f) {
  unsigned u = __float_as_uint(f);
  unsigned r = u + 0x7FFFu + ((u >> 16) & 1u);
  return (unsigned short)(r >> 16);
}

// Kernel 1: r17 structure with two DS-pipe cuts (DS was ~65% busy):
//  (1) rank keys stored as u32 af-bits (af > 0 strictly -> positive-float
//      order == unsigned-bit order; ties handled with unrolled-constant j:
//      (bits_j > bits_me) || (bits_j == bits_me && j < lane) — IDENTICAL
//      selection rule to the r7/r14-verified forms). Rank reads 32->16 b128.
//  (2) AV in 4 groups x 8 tokens, b64 V-reads + pk_fma; combine via
//      xor16+xor32; b64 stores. AV is fmaf tolerance region.
// Scoring chain (dot/max/exp/sums/divs) untouched — bit-exact np emulation.
__global__ __launch_bounds__(512, 4) void attn_topk_kernel(
    const float* __restrict__ qkvp,        // [NW, NTOK, 4*CDIM]
    const float* __restrict__ pfa_values,  // [NW, NH, NTOK, TKIN]
    const int*   __restrict__ pfa_indices, // [NW, NH, NTOK, TKIN]
    const int*   __restrict__ rpi,         // [NTOK, NTOK]
    const float* __restrict__ bias_table,  // [961, NH]
    float* __restrict__ xattn,             // [NW*NTOK, CDIM] (pre-projection, = out region)
    float* __restrict__ vals_out,          // [NW, NH, NTOK, TKOUT]
    float* __restrict__ idx_out)           // [NW, NH, NTOK, TKOUT] (as floats)
{
  __shared__ __align__(16) float k_s[NTOK * KSTR];   // 36,864 B
  __shared__ __align__(16) float v_s[NTOK * KSTR];   // 36,864 B
  __shared__ __align__(16) unsigned key_buf[8 * 64]; //  2,048 B (u32 keys)
  __shared__ __align__(16) float sel_val[8 * 32];    //  1,024 B
  __shared__ __align__(16) int   sel_idx[8 * 32];    //  1,024 B -> 77,824

  const int bx    = blockIdx.x;            // 0..511
  const int b     = bx >> 3;
  const int h     = (bx >> 1) & 3;
  const int qhalf = bx & 1;
  const int tid   = threadIdx.x;
  const int lane  = tid & 63;
  const int wid   = tid >> 6;              // 0..7

  const float SCALE_F = 0.17677669529663687f;  // fl32(32^-0.5)
  const float EPS_F   = 1e-10f;

  const float* qbase = qkvp + (size_t)b * (NTOK * 4 * CDIM);

  // Stage K (part 1) and V (part 2) for this (b,h): 256 tokens x 32 dims.
  #pragma unroll 4
  for (int l = 0; l < 16; ++l) {
    int e   = l * 512 + tid;
    int tok = e >> 5, d = e & 31;
    int g   = tok * 512 + h * 32 + d;
    k_s[tok * KSTR + d] = qbase[g + 128];
    v_s[tok * KSTR + d] = qbase[g + 256];
  }
  __syncthreads();

  const int i0 = qhalf * 128 + wid * 16;   // this wave's first row
  const size_t rowbase = (size_t)((b * NH + h) * NTOK + i0);
  const int*   idx_p = pfa_indices + rowbase * TKIN + lane;
  const float* val_p = pfa_values  + rowbase * TKIN + lane;

  // AV lane roles: 4 groups of 16 lanes; group qh handles 8 tokens, lane
  // covers output dims d = 2*d2, 2*d2+1.
  const int qh = lane >> 4;                // 0..3
  const int d2 = lane & 15;                // 0..15

  // Prologue: fill the 3-deep pipeline (rows 0,1,2 kidx/pv; rpi/bias 0,1)
  int   kx0 = idx_p[0],        kx1 = idx_p[TKIN],      kx2 = idx_p[2 * TKIN];
  float pv0 = val_p[0],        pv1 = val_p[TKIN],      pv2 = val_p[2 * TKIN];
  int   rp0 = rpi[(i0 + 0) * NTOK + kx0];
  int   rp1 = rpi[(i0 + 1) * NTOK + kx1];
  float bi0 = bias_table[rp0 * NH + h];
  float bi1 = bias_table[rp1 * NH + h];
  float4 qv[8];
  #pragma unroll
  for (int u = 0; u < 8; ++u)
    qv[u] = ((const float4*)(qbase + i0 * 512 + h * 32))[u];

  for (int r = 0; r < 16; ++r) {
    const int i = i0 + r;
    const size_t rowoff = rowbase + r;
    const int r1 = (r + 1 < 16) ? r + 1 : 15;
    const int r2 = (r + 2 < 16) ? r + 2 : 15;
    const int r3 = (r + 3 < 16) ? r + 3 : 15;

    // ---- pipeline issues: independents + aged-dependency links
    const int   kx3 = idx_p[r3 * TKIN];
    const float pv3 = val_p[r3 * TKIN];
    const int   rp2 = rpi[(i0 + r2) * NTOK + kx2];     // kx2 is 1 row old
    float4 qn[8];
    #pragma unroll
    for (int u = 0; u < 8; ++u)
      qn[u] = ((const float4*)(qbase + (i0 + r1) * 512 + h * 32))[u];
    const float2 lepe2 =
        *(const float2*)(qbase + i * 512 + 384 + h * 32 + 2 * d2);

    // QK dot (bit-exact np einsum emulation, packed + b128 K reads)
    const float dot = np_dot32(qv, &k_s[kx0 * KSTR], SCALE_F);
    const float s   = __fadd_rn(dot, bi0);

    // softmax over the 64 keys (one per lane); np-structured sums
    float m  = wave_max64f(s);
    float ex = cephes_expf(__fsub_rn(s, m));
    float sm = np_pairwise_sum64(ex, lane);
    float p0 = __fdiv_rn(ex, sm);
    float a  = __fmul_rn(p0, pv0);             // modulate by prior values
    float s2 = np_pairwise_sum64(a, lane);
    float af = __fdiv_rn(__fadd_rn(a, EPS_F), __fadd_rn(s2, EPS_F));

    // issue bias[r+2] now (rp2 issued ~500cyc ago; consumed in ~1.5 rows)
    const float bi2 = bias_table[rp2 * NH + h];

    // stable descending rank via u32 af-bits (af > 0 -> bit order == value
    // order); ties -> lower slot via unrolled-constant j compare.
    const unsigned kme = __float_as_uint(af);
    key_buf[wid * 64 + lane] = kme;
    int rank = 0;
    const uint4* kb4 = (const uint4*)&key_buf[wid * 64];
    #pragma unroll
    for (int j4 = 0; j4 < 16; ++j4) {
      uint4 kk = kb4[j4];
      int j = j4 * 4;
      rank += (kk.x > kme || (kk.x == kme && (j + 0) < lane)) ? 1 : 0;
      rank += (kk.y > kme || (kk.y == kme && (j + 1) < lane)) ? 1 : 0;
      rank += (kk.z > kme || (kk.z == kme && (j + 2) < lane)) ? 1 : 0;
      rank += (kk.w > kme || (kk.w == kme && (j + 3) < lane)) ? 1 : 0;
    }

    // selection: ranks are a permutation of 0..63 -> push to lane=rank
    float selv = __uint_as_float(
        __builtin_amdgcn_ds_permute(rank << 2, __float_as_uint(af)));
    int   seli = __builtin_amdgcn_ds_permute(rank << 2, kx0);
    if (lane < TKOUT) {
      vals_out[rowoff * TKOUT + lane] = selv;         // coalesced
      idx_out [rowoff * TKOUT + lane] = (float)seli;  // coalesced
      sel_val[wid * 32 + lane] = selv;
      sel_idx[wid * 32 + lane] = seli;
    }

    // AV: 4 groups x 8 tokens; b64 V reads (d=2*d2,2*d2+1), pk_fma;
    // combine across groups via xor16 + xor32 (tolerance region).
    const float4* sv4 = (const float4*)&sel_val[wid * 32 + qh * 8];
    const int4*   si4 = (const int4*)  &sel_idx[wid * 32 + qh * 8];
    f32x2 oacc2; oacc2.x = 0.0f; oacc2.y = 0.0f;
    #pragma unroll
    for (int g = 0; g < 2; ++g) {
      float4 vv = sv4[g];
      int4   ii = si4[g];
      f32x2 w0 = *(const f32x2*)&v_s[ii.x * KSTR + 2 * d2];
      f32x2 w1 = *(const f32x2*)&v_s[ii.y * KSTR + 2 * d2];
      f32x2 w2 = *(const f32x2*)&v_s[ii.z * KSTR + 2 * d2];
      f32x2 w3 = *(const f32x2*)&v_s[ii.w * KSTR + 2 * d2];
      f32x2 c0; c0.x = vv.x; c0.y = vv.x;
      f32x2 c1; c1.x = vv.y; c1.y = vv.y;
      f32x2 c2; c2.x = vv.z; c2.y = vv.z;
      f32x2 c3; c3.x = vv.w; c3.y = vv.w;
      oacc2 = oacc2 + c0 * w0;
      oacc2 = oacc2 + c1 * w1;
      oacc2 = oacc2 + c2 * w2;
      oacc2 = oacc2 + c3 * w3;
    }
    oacc2.x += __shfl_xor(oacc2.x, 16);
    oacc2.y += __shfl_xor(oacc2.y, 16);
    oacc2.x += __shfl_xor(oacc2.x, 32);
    oacc2.y += __shfl_xor(oacc2.y, 32);
    if (lane < 16) {
      float2 o2;
      o2.x = oacc2.x + lepe2.x;
      o2.y = oacc2.y + lepe2.y;
      *(float2*)&xattn[(size_t)(b * NTOK + i) * CDIM + h * 32 + 2 * d2] = o2;
    }

    // rotate pipeline registers
    kx0 = kx1; kx1 = kx2; kx2 = kx3;
    pv0 = pv1; pv1 = pv2; pv2 = pv3;
    bi0 = bi1; bi1 = bi2;
    #pragma unroll
    for (int u = 0; u < 8; ++u) qv[u] = qn[u];
  }
}

// Kernel 2: bf16-MFMA in-place projection (round-19 verified; absmax 0.031
// vs threshold 5.1). 64 rows per 256-thread block; W staged as bf16 in LDS.
__global__ __launch_bounds__(256, 2) void proj_mfma_kernel(
    float* __restrict__ x_out,            // [NW*NTOK, CDIM], read then overwritten
    const float* __restrict__ proj_w,     // [CDIM, CDIM]  (out_c, in_c)
    const float* __restrict__ proj_b)     // [CDIM]
{
  __shared__ __align__(16) unsigned short w_lds[CDIM * 136];  // bf16, 34,816 B

  const int tid  = threadIdx.x;
  const int lane = tid & 63;
  const int wid  = tid >> 6;               // 0..3

  // Stage W as bf16: 4096 float4s over 256 threads = 16 each.
  const float4* w4p = (const float4*)proj_w;
  #pragma unroll 4
  for (int l = 0; l < 16; ++l) {
    int idx = l * 256 + tid;               // float4 index
    int oc  = idx >> 5, ic4 = idx & 31;
    float4 w4 = w4p[idx];
    unsigned short* dst = &w_lds[oc * 136 + ic4 * 4];
    dst[0] = f32_to_bf16(w4.x);
    dst[1] = f32_to_bf16(w4.y);
    dst[2] = f32_to_bf16(w4.z);
    dst[3] = f32_to_bf16(w4.w);
  }
  __syncthreads();

  const int rowbase = blockIdx.x * 64 + wid * 16;   // this wave's strip
  const int mrow = lane & 15;                        // A row within strip
  const int kgrp = lane >> 4;                        // k-group (8 elems)

  // Load all 4 A-fragments (K=128 = 4 x 32) for this wave's strip.
  const float* xrow = x_out + (size_t)(rowbase + mrow) * CDIM;
  bf16x8 afr[4];
  #pragma unroll
  for (int kg = 0; kg < 4; ++kg) {
    float4 x0 = *(const float4*)(xrow + kg * 32 + kgrp * 8);
    float4 x1 = *(const float4*)(xrow + kg * 32 + kgrp * 8 + 4);
    afr[kg][0] = (short)f32_to_bf16(x0.x);
    afr[kg][1] = (short)f32_to_bf16(x0.y);
    afr[kg][2] = (short)f32_to_bf16(x0.z);
    afr[kg][3] = (short)f32_to_bf16(x0.w);
    afr[kg][4] = (short)f32_to_bf16(x1.x);
    afr[kg][5] = (short)f32_to_bf16(x1.y);
    afr[kg][6] = (short)f32_to_bf16(x1.z);
    afr[kg][7] = (short)f32_to_bf16(x1.w);
  }

  // 8 column tiles of 16; per tile: 4 MFMA over K, then store immediately.
  #pragma unroll 2
  for (int n = 0; n < 8; ++n) {
    const float bval = proj_b[n * 16 + (lane & 15)];
    f32x4 acc = {0.0f, 0.0f, 0.0f, 0.0f};
    #pragma unroll
    for (int kg = 0; kg < 4; ++kg) {
      bf16x8 bfr = *(const bf16x8*)&w_lds[(n * 16 + (lane & 15)) * 136 +
                                          kg * 32 + kgrp * 8];
      acc = __builtin_amdgcn_mfma_f32_16x16x32_bf16(afr[kg], bfr, acc, 0, 0, 0);
    }
    #pragma unroll
    for (int rr = 0; rr < 4; ++rr) {
      int row = rowbase + kgrp * 4 + rr;
      x_out[(size_t)row * CDIM + n * 16 + (lane & 15)] = acc[rr] + bval;
    }
  }
}

extern "C" void kernel_launch(void* const* d_in, const int* in_sizes, int n_in,
                              void* d_out, int out_size, void* d_ws, size_t ws_size,
                              hipStream_t stream) {
  (void)in_sizes; (void)n_in; (void)d_ws; (void)ws_size; (void)out_size;

  const float* qkvp        = (const float*)d_in[0];
  const float* pfa_values  = (const float*)d_in[1];
  const int*   pfa_indices = (const int*)  d_in[2];
  const int*   rpi         = (const int*)  d_in[3];
  const float* bias_table  = (const float*)d_in[4];
  const float* proj_w      = (const float*)d_in[5];
  const float* proj_b      = (const float*)d_in[6];

  float* out      = (float*)d_out;                       // [NW*NTOK, CDIM]
  float* vals_out = out + (size_t)NW * NTOK * CDIM;      // [NW,NH,NTOK,TKOUT]
  float* idx_out  = vals_out + (size_t)NW * NH * NTOK * TKOUT;

  // Kernel 1 writes pre-projection xattn into the `out` region (same size),
  // plus vals/new_idx. Kernel 2 projects in place (bf16 MFMA).
  attn_topk_kernel<<<NW * NH * 2, 512, 0, stream>>>(
      qkvp, pfa_values, pfa_indices, rpi, bias_table, out, vals_out, idx_out);
  proj_mfma_kernel<<<(NW * NTOK) / 64, 256, 0, stream>>>(out, proj_w, proj_b);
}

// Round 21
// 73.323 us; speedup vs baseline: 1.1957x; 1.1957x over previous
//
#include <hip/hip_runtime.h>
#include <math.h>

#define NW   64      // windows (B_)
#define NTOK 256     // tokens per window (N)
#define CDIM 128     // channels (C)
#define NH   4       // heads (H)
#define HD   32      // head dim
#define TKIN 64      // incoming topk
#define TKOUT 32     // outgoing topk
#define KSTR 36      // K/V LDS row stride (multiple of 4 -> 16B-aligned rows)

typedef float f32x2 __attribute__((ext_vector_type(2)));
typedef short bf16x8 __attribute__((ext_vector_type(8)));   // MFMA A/B frag
typedef float f32x4  __attribute__((ext_vector_type(4)));   // MFMA C/D frag

// DPP lane move (VALU pipe, ~2-4 cyc vs ~40 for ds_bpermute).
template <int CTRL>
static __device__ __forceinline__ float dpp_mov_f(float x) {
  return __int_as_float(__builtin_amdgcn_update_dpp(
      0, __float_as_int(x), CTRL, 0xF, 0xF, true));
}

// Exact full-wave max. Verified round 14. DO NOT TOUCH.
static __device__ __forceinline__ float wave_max64f(float x) {
  x = fmaxf(x, dpp_mov_f<0xB1>(x));    // lane^1
  x = fmaxf(x, dpp_mov_f<0x4E>(x));    // lane^2
  x = fmaxf(x, dpp_mov_f<0x124>(x));   // row_ror:4
  x = fmaxf(x, dpp_mov_f<0x128>(x));   // row_ror:8
  x = fmaxf(x, __int_as_float(
      __builtin_amdgcn_ds_swizzle(__float_as_int(x), 0x401F)));  // lane^16
  x = fmaxf(x, __shfl_xor(x, 32));                               // lane^32
  return x;
}

// Classic Cephes expf (np reference bit-match, round 6). DO NOT TOUCH.
static __device__ __forceinline__ float cephes_expf(float x) {
  x = fminf(x, 88.3762626647949f);
  x = fmaxf(x, -88.3762626647949f);
  float fx = __fadd_rn(__fmul_rn(x, 1.44269504088896341f), 0.5f);
  fx = floorf(fx);
  float tmp = __fmul_rn(fx, 0.693359375f);
  float z2  = __fmul_rn(fx, -2.12194440e-4f);
  x = __fsub_rn(x, tmp);
  x = __fsub_rn(x, z2);
  float z = __fmul_rn(x, x);
  float y = 1.9875691500E-4f;
  y = __fadd_rn(__fmul_rn(y, x), 1.3981999507E-3f);
  y = __fadd_rn(__fmul_rn(y, x), 8.3334519073E-3f);
  y = __fadd_rn(__fmul_rn(y, x), 4.1665795894E-2f);
  y = __fadd_rn(__fmul_rn(y, x), 1.6666665459E-1f);
  y = __fadd_rn(__fmul_rn(y, x), 5.0000001201E-1f);
  y = __fadd_rn(__fmul_rn(y, z), x);
  y = __fadd_rn(y, 1.0f);
  int n = __float2int_rz(fx);              // fx is integral
  float p2n = __int_as_float((n + 127) << 23);
  return __fmul_rn(y, p2n);
}

// numpy pairwise_sum n=64, bit-exact, DPP stage-2. Verified r14. DO NOT TOUCH.
static __device__ __forceinline__ float np_pairwise_sum64(float x, int lane) {
  int k = lane & 7;
  float r = __shfl(x, k);
  #pragma unroll
  for (int i2 = 1; i2 < 8; ++i2) r = __fadd_rn(r, __shfl(x, k + 8 * i2));
  float u = __fadd_rn(r, dpp_mov_f<0xB1>(r));    // + r[l^1]
  float v = __fadd_rn(u, dpp_mov_f<0x4E>(u));    // + u[l^2]
  float w = __fadd_rn(v, dpp_mov_f<0x124>(v));   // + v[l^4]
  return w;
}

// np einsum dot emulation, packed-f32, b128 K reads. Verified r10/r14.
// DO NOT TOUCH.
static __device__ __forceinline__ float np_dot32(const float4* __restrict__ q4,
                                                 const float* __restrict__ krow,
                                                 float scale) {
#pragma clang fp contract(off)
  const float4* k4p = (const float4*)krow;  // 16B-aligned
  f32x2 sc; sc.x = scale; sc.y = scale;
  f32x2 A01; A01.x = 0.0f; A01.y = 0.0f;
  f32x2 A23; A23.x = 0.0f; A23.y = 0.0f;
  #pragma unroll
  for (int i4 = 0; i4 < 8; ++i4) {
    float4 q = q4[i4];
    float4 kk = k4p[i4];
    f32x2 q01; q01.x = q.x; q01.y = q.y;
    f32x2 q23; q23.x = q.z; q23.y = q.w;
    f32x2 k01; k01.x = kk.x; k01.y = kk.y;
    f32x2 k23; k23.x = kk.z; k23.y = kk.w;
    A01 = A01 + (q01 * sc) * k01;
    A23 = A23 + (q23 * sc) * k23;
  }
  f32x2 R = A01 + A23;                    // (acc0+acc2, acc1+acc3)
  return __fadd_rn(R.x, R.y);
}

// f32 -> bf16, round-to-nearest-even (finite data; no NaN handling needed).
static __device__ __forceinline__ unsigned short f32_to_bf16(float f) {
  unsigned u = __float_as_uint(f);
  unsigned r = u + 0x7FFFu + ((u >> 16) & 1u);
  return (unsigned short)(r >> 16);
}

// Kernel 1 (ROUND-17/19 CONFIGURATION VERBATIM — verified optimum of the
// 21-round search: 74.1us attn. Probed-and-rejected: occupancy (r8/r12/
// r13/r18: pinned ~16 waves/CU), per-wave ILP (r11/r15/r16: >64-VGPR
// loses), DS restructure (r20: +VALU +conflicts). Wins kept: DPP shuffles
// + b128 K-gather (r14), 3-deep gather pipeline (r9/r10).)
__global__ __launch_bounds__(512, 4) void attn_topk_kernel(
    const float* __restrict__ qkvp,        // [NW, NTOK, 4*CDIM]
    const float* __restrict__ pfa_values,  // [NW, NH, NTOK, TKIN]
    const int*   __restrict__ pfa_indices, // [NW, NH, NTOK, TKIN]
    const int*   __restrict__ rpi,         // [NTOK, NTOK]
    const float* __restrict__ bias_table,  // [961, NH]
    float* __restrict__ xattn,             // [NW*NTOK, CDIM] (pre-projection, = out region)
    float* __restrict__ vals_out,          // [NW, NH, NTOK, TKOUT]
    float* __restrict__ idx_out)           // [NW, NH, NTOK, TKOUT] (as floats)
{
  __shared__ __align__(16) float k_s[NTOK * KSTR];   // 36,864 B
  __shared__ __align__(16) float v_s[NTOK * KSTR];   // 36,864 B
  __shared__ __align__(16) unsigned long long key_buf[8 * 64];  // 4,096 B
  __shared__ __align__(16) float sel_val[8 * 32];    // 1,024 B
  __shared__ __align__(16) int   sel_idx[8 * 32];    // 1,024 B -> 79,872 total

  const int bx    = blockIdx.x;            // 0..511
  const int b     = bx >> 3;
  const int h     = (bx >> 1) & 3;
  const int qhalf = bx & 1;
  const int tid   = threadIdx.x;
  const int lane  = tid & 63;
  const int wid   = tid >> 6;              // 0..7

  const float SCALE_F = 0.17677669529663687f;  // fl32(32^-0.5)
  const float EPS_F   = 1e-10f;

  const float* qbase = qkvp + (size_t)b * (NTOK * 4 * CDIM);

  // Stage K (part 1) and V (part 2) for this (b,h): 256 tokens x 32 dims.
  #pragma unroll 4
  for (int l = 0; l < 16; ++l) {
    int e   = l * 512 + tid;
    int tok = e >> 5, d = e & 31;
    int g   = tok * 512 + h * 32 + d;
    k_s[tok * KSTR + d] = qbase[g + 128];
    v_s[tok * KSTR + d] = qbase[g + 256];
  }
  __syncthreads();

  const int i0 = qhalf * 128 + wid * 16;   // this wave's first row
  const size_t rowbase = (size_t)((b * NH + h) * NTOK + i0);
  const int*   idx_p = pfa_indices + rowbase * TKIN + lane;
  const float* val_p = pfa_values  + rowbase * TKIN + lane;

  // Prologue: fill the 3-deep pipeline (rows 0,1,2 kidx/pv; rpi/bias 0,1)
  int   kx0 = idx_p[0],        kx1 = idx_p[TKIN],      kx2 = idx_p[2 * TKIN];
  float pv0 = val_p[0],        pv1 = val_p[TKIN],      pv2 = val_p[2 * TKIN];
  int   rp0 = rpi[(i0 + 0) * NTOK + kx0];
  int   rp1 = rpi[(i0 + 1) * NTOK + kx1];
  float bi0 = bias_table[rp0 * NH + h];
  float bi1 = bias_table[rp1 * NH + h];
  float4 qv[8];
  #pragma unroll
  for (int u = 0; u < 8; ++u)
    qv[u] = ((const float4*)(qbase + i0 * 512 + h * 32))[u];

  for (int r = 0; r < 16; ++r) {
    const int i = i0 + r;
    const size_t rowoff = rowbase + r;
    const int r1 = (r + 1 < 16) ? r + 1 : 15;
    const int r2 = (r + 2 < 16) ? r + 2 : 15;
    const int r3 = (r + 3 < 16) ? r + 3 : 15;

    // ---- pipeline issues: independents + aged-dependency links
    const int   kx3 = idx_p[r3 * TKIN];
    const float pv3 = val_p[r3 * TKIN];
    const int   rp2 = rpi[(i0 + r2) * NTOK + kx2];     // kx2 is 1 row old
    float4 qn[8];
    #pragma unroll
    for (int u = 0; u < 8; ++u)
      qn[u] = ((const float4*)(qbase + (i0 + r1) * 512 + h * 32))[u];
    const float lepe = qbase[i * 512 + 384 + h * 32 + (lane & 31)];

    // QK dot (bit-exact np einsum emulation, packed + b128 K reads)
    const float dot = np_dot32(qv, &k_s[kx0 * KSTR], SCALE_F);
    const float s   = __fadd_rn(dot, bi0);

    // softmax over the 64 keys (one per lane); np-structured sums
    float m  = wave_max64f(s);
    float ex = cephes_expf(__fsub_rn(s, m));
    float sm = np_pairwise_sum64(ex, lane);
    float p0 = __fdiv_rn(ex, sm);
    float a  = __fmul_rn(p0, pv0);             // modulate by prior values
    float s2 = np_pairwise_sum64(a, lane);
    float af = __fdiv_rn(__fadd_rn(a, EPS_F), __fadd_rn(s2, EPS_F));

    // issue bias[r+2] now (rp2 issued ~500cyc ago; consumed in ~1.5 rows)
    const float bi2 = bias_table[rp2 * NH + h];

    // stable descending rank via u64 keys: (af_bits<<32)|(63-lane).
    const unsigned long long kme =
        ((unsigned long long)__float_as_uint(af) << 32) | (unsigned)(63 - lane);
    key_buf[wid * 64 + lane] = kme;
    int rank = 0;
    const ulonglong2* kb2 = (const ulonglong2*)&key_buf[wid * 64];
    #pragma unroll
    for (int j2 = 0; j2 < 32; ++j2) {
      ulonglong2 kk = kb2[j2];
      rank += (kk.x > kme) ? 1 : 0;
      rank += (kk.y > kme) ? 1 : 0;
    }

    // selection: ranks are a permutation of 0..63 -> push to lane=rank
    float selv = __uint_as_float(
        __builtin_amdgcn_ds_permute(rank << 2, __float_as_uint(af)));
    int   seli = __builtin_amdgcn_ds_permute(rank << 2, kx0);
    if (lane < TKOUT) {
      vals_out[rowoff * TKOUT + lane] = selv;         // coalesced
      idx_out [rowoff * TKOUT + lane] = (float)seli;  // coalesced
      sel_val[wid * 32 + lane] = selv;
      sel_idx[wid * 32 + lane] = seli;
    }

    // AV: lanes (ph,d); sel via b128 broadcasts; fmaf (tolerance region)
    const int ph = lane >> 5, d = lane & 31;
    const float4* sv4 = (const float4*)&sel_val[wid * 32 + ph * 16];
    const int4*   si4 = (const int4*)  &sel_idx[wid * 32 + ph * 16];
    float oacc = 0.0f;
    #pragma unroll
    for (int g = 0; g < 4; ++g) {
      float4 vv = sv4[g];
      int4   ii = si4[g];
      oacc = fmaf(vv.x, v_s[ii.x * KSTR + d], oacc);
      oacc = fmaf(vv.y, v_s[ii.y * KSTR + d], oacc);
      oacc = fmaf(vv.z, v_s[ii.z * KSTR + d], oacc);
      oacc = fmaf(vv.w, v_s[ii.w * KSTR + d], oacc);
    }
    oacc += __shfl_xor(oacc, 32);
    if (ph == 0) {
      xattn[(size_t)(b * NTOK + i) * CDIM + h * 32 + d] = oacc + lepe;
    }

    // rotate pipeline registers
    kx0 = kx1; kx1 = kx2; kx2 = kx3;
    pv0 = pv1; pv1 = pv2; pv2 = pv3;
    bi0 = bi1; bi1 = bi2;
    #pragma unroll
    for (int u = 0; u < 8; ++u) qv[u] = qn[u];
  }
}

// Kernel 2: bf16-MFMA in-place projection (round-19 verified; absmax 0.031
// vs threshold 5.1). 64 rows per 256-thread block; W staged as bf16 in LDS.
__global__ __launch_bounds__(256, 2) void proj_mfma_kernel(
    float* __restrict__ x_out,            // [NW*NTOK, CDIM], read then overwritten
    const float* __restrict__ proj_w,     // [CDIM, CDIM]  (out_c, in_c)
    const float* __restrict__ proj_b)     // [CDIM]
{
  __shared__ __align__(16) unsigned short w_lds[CDIM * 136];  // bf16, 34,816 B

  const int tid  = threadIdx.x;
  const int lane = tid & 63;
  const int wid  = tid >> 6;               // 0..3

  // Stage W as bf16: 4096 float4s over 256 threads = 16 each.
  const float4* w4p = (const float4*)proj_w;
  #pragma unroll 4
  for (int l = 0; l < 16; ++l) {
    int idx = l * 256 + tid;               // float4 index
    int oc  = idx >> 5, ic4 = idx & 31;
    float4 w4 = w4p[idx];
    unsigned short* dst = &w_lds[oc * 136 + ic4 * 4];
    dst[0] = f32_to_bf16(w4.x);
    dst[1] = f32_to_bf16(w4.y);
    dst[2] = f32_to_bf16(w4.z);
    dst[3] = f32_to_bf16(w4.w);
  }
  __syncthreads();

  const int rowbase = blockIdx.x * 64 + wid * 16;   // this wave's strip
  const int mrow = lane & 15;                        // A row within strip
  const int kgrp = lane >> 4;                        // k-group (8 elems)

  // Load all 4 A-fragments (K=128 = 4 x 32) for this wave's strip.
  const float* xrow = x_out + (size_t)(rowbase + mrow) * CDIM;
  bf16x8 afr[4];
  #pragma unroll
  for (int kg = 0; kg < 4; ++kg) {
    float4 x0 = *(const float4*)(xrow + kg * 32 + kgrp * 8);
    float4 x1 = *(const float4*)(xrow + kg * 32 + kgrp * 8 + 4);
    afr[kg][0] = (short)f32_to_bf16(x0.x);
    afr[kg][1] = (short)f32_to_bf16(x0.y);
    afr[kg][2] = (short)f32_to_bf16(x0.z);
    afr[kg][3] = (short)f32_to_bf16(x0.w);
    afr[kg][4] = (short)f32_to_bf16(x1.x);
    afr[kg][5] = (short)f32_to_bf16(x1.y);
    afr[kg][6] = (short)f32_to_bf16(x1.z);
    afr[kg][7] = (short)f32_to_bf16(x1.w);
  }

  // 8 column tiles of 16; per tile: 4 MFMA over K, then store immediately.
  #pragma unroll 2
  for (int n = 0; n < 8; ++n) {
    const float bval = proj_b[n * 16 + (lane & 15)];
    f32x4 acc = {0.0f, 0.0f, 0.0f, 0.0f};
    #pragma unroll
    for (int kg = 0; kg < 4; ++kg) {
      bf16x8 bfr = *(const bf16x8*)&w_lds[(n * 16 + (lane & 15)) * 136 +
                                          kg * 32 + kgrp * 8];
      acc = __builtin_amdgcn_mfma_f32_16x16x32_bf16(afr[kg], bfr, acc, 0, 0, 0);
    }
    #pragma unroll
    for (int rr = 0; rr < 4; ++rr) {
      int row = rowbase + kgrp * 4 + rr;
      x_out[(size_t)row * CDIM + n * 16 + (lane & 15)] = acc[rr] + bval;
    }
  }
}

extern "C" void kernel_launch(void* const* d_in, const int* in_sizes, int n_in,
                              void* d_out, int out_size, void* d_ws, size_t ws_size,
                              hipStream_t stream) {
  (void)in_sizes; (void)n_in; (void)d_ws; (void)ws_size; (void)out_size;

  const float* qkvp        = (const float*)d_in[0];
  const float* pfa_values  = (const float*)d_in[1];
  const int*   pfa_indices = (const int*)  d_in[2];
  const int*   rpi         = (const int*)  d_in[3];
  const float* bias_table  = (const float*)d_in[4];
  const float* proj_w      = (const float*)d_in[5];
  const float* proj_b      = (const float*)d_in[6];

  float* out      = (float*)d_out;                       // [NW*NTOK, CDIM]
  float* vals_out = out + (size_t)NW * NTOK * CDIM;      // [NW,NH,NTOK,TKOUT]
  float* idx_out  = vals_out + (size_t)NW * NH * NTOK * TKOUT;

  // Kernel 1 writes pre-projection xattn into the `out` region (same size),
  // plus vals/new_idx. Kernel 2 projects in place (bf16 MFMA).
  attn_topk_kernel<<<NW * NH * 2, 512, 0, stream>>>(
      qkvp, pfa_values, pfa_indices, rpi, bias_table, out, vals_out, idx_out);
  proj_mfma_kernel<<<(NW * NTOK) / 64, 256, 0, stream>>>(out, proj_w, proj_b);
}